// Round 9
// baseline (83.637 us; speedup 1.0000x reference)
//
#include <hip/hip_runtime.h>
#include <hip/hip_bf16.h>
#include <stdint.h>

#define N 8192
#define K 64

typedef __attribute__((ext_vector_type(8))) __bf16 bf16x8;
typedef __attribute__((ext_vector_type(4))) float f32x4;
typedef __attribute__((address_space(3))) uint8_t lds_u8;
typedef __attribute__((address_space(1))) const uint8_t glob_u8;

// ws layout:
//   [0, 1MB)               : W0 = F_ll as bf16 (ushort), 8192*64
//   [1MB, 1MB+16KB)        : P1 term1 per-block partials (4096 f32)
//   [1MB+64KB, +4MB)       : P2 term2 per-block partial G (256 * 4096 f32)
//   [0x510000, +256B)      : R1 stage2 partials (64 f32)
//   [0x510400, +256B)      : R2 stage2 partials (64 f32)
//   [0x510800, +4B)        : cnt (last-block counter)

static __device__ __forceinline__ uint32_t f2bf(float f) {
  uint32_t x = __float_as_uint(f);
  return (x + 0x7FFFu + ((x >> 16) & 1u)) >> 16;  // RNE f32->bf16
}

// dispatch 1: f32 -> bf16 convert (R1-proven) + cnt reset. 3 MB traffic, ~2 us.
__global__ __launch_bounds__(256) void convert_kernel(const float* __restrict__ in,
                                                      uint4* __restrict__ out,
                                                      unsigned* __restrict__ cnt) {
  int t = blockIdx.x * 256 + threadIdx.x;  // 65536 threads x 8 elems
  if (t == 0) *cnt = 0u;
  const float4* p = (const float4*)in;
  float4 a = p[2 * t], b = p[2 * t + 1];
  float v[8] = {a.x, a.y, a.z, a.w, b.x, b.y, b.z, b.w};
  uint32_t r[8];
#pragma unroll
  for (int i = 0; i < 8; ++i) r[i] = f2bf(v[i]);
  uint4 o;
  o.x = r[0] | (r[1] << 16);
  o.y = r[2] | (r[3] << 16);
  o.z = r[4] | (r[5] << 16);
  o.w = r[6] | (r[7] << 16);
  out[t] = o;
}

// dispatch 2: grid-fused term2 + term1.
//  blocks 0..255    : term2 (32 rows each, f32, R5-proven form) -> P2
//  blocks 256..4351 : term1, R2-EXACT structure (64x256 Theta tile, bj-inner,
//                     __syncthreads double-buffer, global_load_lds 16B) -> P1
__global__ __launch_bounds__(256) void fused_kernel(const float* __restrict__ Theta,
                                                    const float* __restrict__ Fll,
                                                    const float* __restrict__ Ful,
                                                    const ushort* __restrict__ Fb,
                                                    float* __restrict__ P1,
                                                    float* __restrict__ P2) {
  __shared__ float pool[2 * 16 * 260 + 8];  // 33.3 KB (term2 needs 16 KB)
  const int t = threadIdx.x;

  if (blockIdx.x < 256) {
    // ---------------- term2 ----------------
    float(*sll)[64] = (float(*)[64])pool;
    float(*sul)[64] = (float(*)[64])(pool + 2048);
    const int j = t & 63, kq = t >> 6;  // kq uniform per wave -> broadcast reads
    const size_t r0 = (size_t)blockIdx.x * 32;

    for (int i = t; i < 512; i += 256) {  // 32*64 f32 = 512 float4 per matrix
      ((float4*)sll)[i] = ((const float4*)(Fll + r0 * K))[i];
      ((float4*)sul)[i] = ((const float4*)(Ful + r0 * K))[i];
    }
    __syncthreads();

    float acc[16];
#pragma unroll
    for (int m = 0; m < 16; ++m) acc[m] = 0.f;
    for (int r = 0; r < 32; ++r) {
      float fl = sll[r][j];
#pragma unroll
      for (int m = 0; m < 16; ++m) acc[m] += sul[r][kq * 16 + m] * fl;
    }
#pragma unroll
    for (int m = 0; m < 16; ++m)
      P2[(size_t)blockIdx.x * 4096 + (kq * 16 + m) * 64 + j] = acc[m];
    return;
  }

  // ---------------- term1 (R2-exact) ----------------
  const int bid = blockIdx.x - 256;
  const int lane = t & 63, wave = t >> 6;
  const int bi = bid >> 5;  // 128 i-tiles
  const int bj = bid & 31;  // 32 j-tiles (inner: sequential Theta sweep)
  const int i0 = bi * 64;
  const int jc0 = bj * 256;
  const int l15 = lane & 15, lg = lane >> 4;

  float* lds0 = pool;
  float* lds1 = pool + 16 * 260;

  // stage strip s: wave w loads strip-rows {w, w+4, w+8, w+12}, 1 KB each.
#define STAGE(s, lbuf)                                                              \
  {                                                                                 \
    _Pragma("unroll") for (int q = 0; q < 4; ++q) {                                 \
      int row = wave + 4 * q;                                                       \
      const float* g = Theta + (size_t)(i0 + (s)*16 + row) * N + jc0 + lane * 4;    \
      float* l = (lbuf) + row * 260;                                                \
      __builtin_amdgcn_global_load_lds((glob_u8*)g, (lds_u8*)l, 16, 0, 0);          \
    }                                                                               \
  }

  STAGE(0, lds0);

  bf16x8 afrag[4][2], bfrag[4][2];
#pragma unroll
  for (int m = 0; m < 4; ++m)
#pragma unroll
    for (int ks = 0; ks < 2; ++ks)
      afrag[m][ks] = *(const bf16x8*)&Fb[(size_t)(i0 + m * 16 + l15) * K + ks * 32 + lg * 8];
#pragma unroll
  for (int n = 0; n < 4; ++n)
#pragma unroll
    for (int ks = 0; ks < 2; ++ks)
      bfrag[n][ks] =
          *(const bf16x8*)&Fb[(size_t)(jc0 + wave * 64 + n * 16 + l15) * K + ks * 32 + lg * 8];

  float p = 0.f;
  __syncthreads();
#pragma unroll
  for (int s = 0; s < 4; ++s) {
    float* cur = (s & 1) ? lds1 : lds0;
    if (s < 3) STAGE(s + 1, (s & 1) ? lds0 : lds1);
    f32x4 zero = {0.f, 0.f, 0.f, 0.f};
    f32x4 acc[4] = {zero, zero, zero, zero};
#pragma unroll
    for (int jf = 0; jf < 4; ++jf)
#pragma unroll
      for (int ks = 0; ks < 2; ++ks)
        acc[jf] = __builtin_amdgcn_mfma_f32_16x16x32_bf16(afrag[s][ks], bfrag[jf][ks],
                                                          acc[jf], 0, 0, 0);
#pragma unroll
    for (int jf = 0; jf < 4; ++jf)
#pragma unroll
      for (int r = 0; r < 4; ++r)
        p += acc[jf][r] * cur[(lg * 4 + r) * 260 + wave * 64 + jf * 16 + l15];
    __syncthreads();
  }

#pragma unroll
  for (int off = 32; off > 0; off >>= 1) p += __shfl_down(p, off, 64);
  if (lane == 0) pool[wave] = p;
  __syncthreads();
  if (t == 0) P1[bid] = (pool[0] + pool[1]) + (pool[2] + pool[3]);
}

// dispatch 3: stage2 + final merged (last-block pattern, proven). 64 blocks;
// block b sums P1 slice [b*64,+64) and finishes G cols kj in [b*64,+64) over
// the 256 term2 partials, squaring.
__global__ __launch_bounds__(256) void stage2_kernel(const float* __restrict__ P1,
                                                     const float* __restrict__ P2,
                                                     const float* __restrict__ lam,
                                                     float* __restrict__ out,
                                                     float* __restrict__ R1,
                                                     float* __restrict__ R2,
                                                     unsigned* __restrict__ cnt) {
  __shared__ float sg[4][64];
  __shared__ unsigned is_last;
  const int t = threadIdx.x, b = blockIdx.x;
  const int l = t & 63, q = t >> 6;
  const int kj = b * 64 + l;
  float gp = 0.f;
  for (int blk = q * 64; blk < q * 64 + 64; ++blk) gp += P2[(size_t)blk * 4096 + kj];
  sg[q][l] = gp;
  float a = (t < 64) ? P1[b * 64 + t] : 0.f;
  __syncthreads();
  if (q == 0) {
    float g = (sg[0][l] + sg[1][l]) + (sg[2][l] + sg[3][l]);
    float r2 = g * g;
    float r1 = a;
#pragma unroll
    for (int off = 32; off > 0; off >>= 1) {
      r2 += __shfl_down(r2, off, 64);
      r1 += __shfl_down(r1, off, 64);
    }
    if (l == 0) {
      R1[b] = r1;
      R2[b] = r2;
    }
  }
  if (t == 0) {
    __threadfence();  // publish R1[b]/R2[b]
    unsigned old = atomicAdd(cnt, 1u);
    __threadfence();  // acquire for last block's reads
    is_last = (old == 63u) ? 1u : 0u;
  }
  __syncthreads();
  if (is_last && t < 64) {
    float r1 = R1[t], r2 = R2[t];
#pragma unroll
    for (int off = 32; off > 0; off >>= 1) {
      r1 += __shfl_down(r1, off, 64);
      r2 += __shfl_down(r2, off, 64);
    }
    if (t == 0) out[0] = r1 + lam[0] * r2;
  }
}

extern "C" void kernel_launch(void* const* d_in, const int* in_sizes, int n_in,
                              void* d_out, int out_size, void* d_ws, size_t ws_size,
                              hipStream_t stream) {
  const float* Fll = (const float*)d_in[0];
  const float* Ful = (const float*)d_in[1];
  const float* Theta = (const float*)d_in[2];
  const float* lam = (const float*)d_in[3];
  float* out = (float*)d_out;

  char* ws = (char*)d_ws;
  ushort* W0 = (ushort*)ws;                            // 1 MB bf16 F_ll
  float* P1 = (float*)(ws + (1u << 20));               // 16 KB
  float* P2 = (float*)(ws + (1u << 20) + (1u << 16));  // 4 MB
  float* R1 = (float*)(ws + 0x510000u);
  float* R2 = (float*)(ws + 0x510400u);
  unsigned* cnt = (unsigned*)(ws + 0x510800u);

  convert_kernel<<<256, 256, 0, stream>>>(Fll, (uint4*)W0, cnt);
  fused_kernel<<<4352, 256, 0, stream>>>(Theta, Fll, Ful, W0, P1, P2);
  stage2_kernel<<<64, 256, 0, stream>>>(P1, P2, lam, out, R1, R2, cnt);
}